// Round 1
// baseline (117.032 us; speedup 1.0000x reference)
//
#include <hip/hip_runtime.h>
#include <math.h>

#define T 512
#define NCH 32
#define BATCH 16
#define DM 512

// ---------------------------------------------------------------------------
// Kernel A: per (b,n) brute-force 257-bin DFT; count Nyquist-dominant per b.
// period is ALWAYS 512 (pidx=t) unless argmax bin == 256 (Nyquist) -> period 1
// (pidx=0). So we only need the per-b count of Nyquist-dominant channels.
// ---------------------------------------------------------------------------
__global__ __launch_bounds__(256) void fft_argmax_kernel(const float* __restrict__ x,
                                                         int* __restrict__ cnt) {
    __shared__ float  xcol[T];
    __shared__ float2 tw[T];     // (cos, sin) twiddles
    __shared__ float  s_mag[256];
    __shared__ int    s_idx[256];

    const int tid = threadIdx.x;
    const int b   = blockIdx.x >> 5;
    const int n   = blockIdx.x & 31;

    for (int t = tid; t < T; t += 256) {
        xcol[t] = x[(b * T + t) * NCH + n];
        float s, c;
        sincosf((float)t * 0.012271846303085129f, &s, &c); // 2*pi/512
        tw[t] = make_float2(c, s);
    }
    __syncthreads();

    float best = -1.0f;
    int   bidx = 0;
    // thread 0 handles bins 0 and 256; others one bin each
    for (int k = tid; k < 257; k += 256) {
        float re = 0.0f, im = 0.0f;
        int m = 0;
        #pragma unroll 4
        for (int t = 0; t < T; ++t) {
            float  xv = xcol[t];
            float2 w  = tw[m];
            re = fmaf(xv, w.x, re);
            im = fmaf(xv, w.y, im);
            m = (m + k) & (T - 1);
        }
        float mag = re * re + im * im;
        if (mag > best) { best = mag; bidx = k; }  // ascending k => strict > keeps lower idx
    }
    s_mag[tid] = best;
    s_idx[tid] = bidx;
    __syncthreads();

    for (int s = 128; s > 0; s >>= 1) {
        if (tid < s) {
            float m2 = s_mag[tid + s]; int i2 = s_idx[tid + s];
            float m1 = s_mag[tid];     int i1 = s_idx[tid];
            if (m2 > m1 || (m2 == m1 && i2 < i1)) { s_mag[tid] = m2; s_idx[tid] = i2; }
        }
        __syncthreads();
    }
    if (tid == 0 && s_idx[0] == 256) atomicAdd(&cnt[b], 1);
}

// ---------------------------------------------------------------------------
// Kernel B: fused conv1d(circular,k=3) + temporal embedding + cycle embedding.
// Block = 512 threads (one per d). Each block: one b, 32 consecutive t.
// ---------------------------------------------------------------------------
__global__ __launch_bounds__(512) void fused_kernel(const float* __restrict__ x,
                                                    const int*   __restrict__ xmark,
                                                    const float* __restrict__ conv_w,
                                                    const int*   __restrict__ cnt,
                                                    float*       __restrict__ out) {
    __shared__ float xs[34 * NCH];   // rows t0-1 .. t0+32 (wrapped)
    __shared__ int   sm[32 * 4];
    __shared__ float ttbl[7 * DM];   // temporal table rows p=0..6 (randint(0,7))

    const int tid = threadIdx.x;     // == d
    const int t0  = blockIdx.x * 32;
    const int b   = blockIdx.y;
    const int d   = tid;

    // stage x slab (with circular wrap)
    for (int i = tid; i < 34 * NCH; i += 512) {
        int row = i >> 5, n = i & 31;
        int t = (t0 + row - 1 + T) & (T - 1);
        xs[i] = x[(b * T + t) * NCH + n];
    }
    if (tid < 128) sm[tid] = xmark[(b * T + t0) * 4 + tid];

    // fixed-embedding generator for column d:
    // f(p,d) = sin(p * 10000^{-(d&~1)/512} + (d&1)*pi/2)
    const float dv    = expf((float)(d & ~1) * (-9.210340371976184f / 512.0f));
    const float shift = (d & 1) ? 1.57079632679f : 0.0f;
    for (int p = 0; p < 7; ++p) ttbl[p * DM + d] = sinf((float)p * dv + shift);

    const float f0 = (d & 1) ? 1.0f : 0.0f;     // f(0,d)
    const int   kb = cnt[b];                    // Nyquist-dominant channel count
    const float wk = (float)kb * (1.0f / 32.0f);
    const float wt = (float)(32 - kb) * (1.0f / 32.0f);

    // conv weights for this d: w[n*3+k], 96 floats in registers
    float w[96];
    const float4* wp = (const float4*)(conv_w + d * 96);
    #pragma unroll
    for (int j = 0; j < 24; ++j) {
        float4 v = wp[j];
        w[4 * j + 0] = v.x; w[4 * j + 1] = v.y;
        w[4 * j + 2] = v.z; w[4 * j + 3] = v.w;
    }
    __syncthreads();

    #pragma unroll 1
    for (int tt = 0; tt < 32; ++tt) {
        float acc = 0.0f;
        const float4* r0 = (const float4*)&xs[tt * NCH];        // t-1
        const float4* r1 = (const float4*)&xs[(tt + 1) * NCH];  // t
        const float4* r2 = (const float4*)&xs[(tt + 2) * NCH];  // t+1
        #pragma unroll
        for (int q = 0; q < 8; ++q) {
            float4 a = r0[q], bb = r1[q], c = r2[q];
            int base = q * 12;
            acc = fmaf(a.x,  w[base + 0],  acc);
            acc = fmaf(bb.x, w[base + 1],  acc);
            acc = fmaf(c.x,  w[base + 2],  acc);
            acc = fmaf(a.y,  w[base + 3],  acc);
            acc = fmaf(bb.y, w[base + 4],  acc);
            acc = fmaf(c.y,  w[base + 5],  acc);
            acc = fmaf(a.z,  w[base + 6],  acc);
            acc = fmaf(bb.z, w[base + 7],  acc);
            acc = fmaf(c.z,  w[base + 8],  acc);
            acc = fmaf(a.w,  w[base + 9],  acc);
            acc = fmaf(bb.w, w[base + 10], acc);
            acc = fmaf(c.w,  w[base + 11], acc);
        }
        // temporal: sum of 4 table rows (all indices in [0,7))
        float temp = ttbl[sm[tt * 4 + 0] * DM + d] + ttbl[sm[tt * 4 + 1] * DM + d] +
                     ttbl[sm[tt * 4 + 2] * DM + d] + ttbl[sm[tt * 4 + 3] * DM + d];
        // cycle: weighted mix of f(t,d) and f(0,d)
        int   tg  = t0 + tt;
        float ft  = sinf((float)tg * dv + shift);
        float cyc = wt * ft + wk * f0;
        out[((b * T) + tg) * DM + d] = acc + temp + cyc;
    }
}

extern "C" void kernel_launch(void* const* d_in, const int* in_sizes, int n_in,
                              void* d_out, int out_size, void* d_ws, size_t ws_size,
                              hipStream_t stream) {
    const float* x      = (const float*)d_in[0];
    const int*   xmark  = (const int*)d_in[1];
    const float* conv_w = (const float*)d_in[2];
    float*       out    = (float*)d_out;
    int*         cnt    = (int*)d_ws;

    hipMemsetAsync(cnt, 0, 64, stream);
    fft_argmax_kernel<<<dim3(BATCH * NCH), dim3(256), 0, stream>>>(x, cnt);
    fused_kernel<<<dim3(T / 32, BATCH), dim3(512), 0, stream>>>(x, xmark, conv_w, cnt, out);
}

// Round 2
// 93.828 us; speedup vs baseline: 1.2473x; 1.2473x over previous
//
#include <hip/hip_runtime.h>
#include <math.h>

#define T 512
#define NCH 32
#define BATCH 16
#define DM 512

// ---------------------------------------------------------------------------
// Kernel A: per (b,n) 257-bin DFT argmax reduced to: "does the Nyquist bin
// strictly beat all bins 0..255?"  (every non-Nyquist bin clamps to period
// 512 -> pidx=t; Nyquist clamps to period 1 -> pidx=0).
// Twiddles via in-register rotation recurrence: no LDS table, no conflicts.
// ---------------------------------------------------------------------------
__global__ __launch_bounds__(256) void dft_nyq_kernel(const float* __restrict__ x,
                                                      int* __restrict__ cnt) {
    __shared__ float4 xs4[T / 4];
    __shared__ float  s_mag[256];

    const int tid = threadIdx.x;
    const int b   = blockIdx.x >> 5;
    const int n   = blockIdx.x & 31;

    float* xs = (float*)xs4;
    for (int t = tid; t < T; t += 256)
        xs[t] = x[(b * T + t) * NCH + n];
    __syncthreads();

    // bin k = tid: rotation step e^{i*2*pi*k/512}
    float sd, cd;
    sincospif((float)tid * (1.0f / 256.0f), &sd, &cd);

    float wr = 1.0f, wi = 0.0f;   // e^{i*t*theta}, t starts at 0
    float ar = 0.0f, ai = 0.0f;   // DFT accumulator for bin tid
    float ny = 0.0f;              // Nyquist alternating sum (redundant, uniform)

    #pragma unroll 8
    for (int g = 0; g < T / 4; ++g) {
        float4 xv = xs4[g];                       // broadcast b128
        ny += (xv.x + xv.z) - (xv.y + xv.w);
        // 4 rotate-accumulate steps
        ar = fmaf(xv.x, wr, ar); ai = fmaf(xv.x, wi, ai);
        { float nr = fmaf(wr, cd, -(wi * sd)); float ni = fmaf(wr, sd, wi * cd); wr = nr; wi = ni; }
        ar = fmaf(xv.y, wr, ar); ai = fmaf(xv.y, wi, ai);
        { float nr = fmaf(wr, cd, -(wi * sd)); float ni = fmaf(wr, sd, wi * cd); wr = nr; wi = ni; }
        ar = fmaf(xv.z, wr, ar); ai = fmaf(xv.z, wi, ai);
        { float nr = fmaf(wr, cd, -(wi * sd)); float ni = fmaf(wr, sd, wi * cd); wr = nr; wi = ni; }
        ar = fmaf(xv.w, wr, ar); ai = fmaf(xv.w, wi, ai);
        { float nr = fmaf(wr, cd, -(wi * sd)); float ni = fmaf(wr, sd, wi * cd); wr = nr; wi = ni; }
    }

    s_mag[tid] = ar * ar + ai * ai;
    __syncthreads();
    for (int s2 = 128; s2 > 0; s2 >>= 1) {
        if (tid < s2) s_mag[tid] = fmaxf(s_mag[tid], s_mag[tid + s2]);
        __syncthreads();
    }
    if (tid == 0) {
        float nyq2 = ny * ny;
        // argmax takes the FIRST max: Nyquist (idx 256) must be strictly greater
        if (nyq2 > s_mag[0]) atomicAdd(&cnt[b], 1);
    }
}

// ---------------------------------------------------------------------------
// Kernel B: fused conv1d(circular,k=3) + temporal + cycle embedding.
// Block = 512 threads (one per d), 32 t per block. 4 outputs/group sharing
// 6 staged rows (12 b128/output); sin/cos via rotation recurrence (no libm
// sinf in the hot loop).
// ---------------------------------------------------------------------------
__global__ __launch_bounds__(512, 2) void fused_kernel(const float* __restrict__ x,
                                                       const int*   __restrict__ xmark,
                                                       const float* __restrict__ conv_w,
                                                       const int*   __restrict__ cnt,
                                                       float*       __restrict__ out) {
    __shared__ float xs[34 * NCH];   // rows t0-1 .. t0+32 (wrapped)
    __shared__ int   sm[32 * 4];
    __shared__ float ttbl[7 * DM];   // temporal table rows p=0..6

    const int d  = threadIdx.x;
    const int t0 = blockIdx.x * 32;
    const int b  = blockIdx.y;

    for (int i = d; i < 34 * NCH; i += 512) {
        int row = i >> 5, n = i & 31;
        int t = (t0 + row - 1 + T) & (T - 1);
        xs[i] = x[(b * T + t) * NCH + n];
    }
    if (d < 128) sm[d] = xmark[(b * T + t0) * 4 + d];

    // fixed-embedding generator: f(p,d) = sin(p*dv + (d&1)*pi/2)
    const float dv  = expf((float)(d & ~1) * (-9.210340371976184f / 512.0f));
    float sd_, cd_;
    sincosf(dv, &sd_, &cd_);
    const bool odd = (d & 1);

    // temporal table rows 0..6 via rotation from phi=0
    {
        float s = 0.0f, c = 1.0f;
        #pragma unroll
        for (int p = 0; p < 7; ++p) {
            ttbl[p * DM + d] = odd ? c : s;
            float ns = fmaf(c, sd_, s * cd_);
            float nc = fmaf(c, cd_, -(s * sd_));
            s = ns; c = nc;
        }
    }

    // conv weights for this d
    float w[96];
    const float4* wp = (const float4*)(conv_w + d * 96);
    #pragma unroll
    for (int j = 0; j < 24; ++j) {
        float4 v = wp[j];
        w[4 * j + 0] = v.x; w[4 * j + 1] = v.y;
        w[4 * j + 2] = v.z; w[4 * j + 3] = v.w;
    }

    const float f0 = odd ? 1.0f : 0.0f;
    const int   kb = cnt[b];
    const float wk = (float)kb * (1.0f / 32.0f);
    const float wt = (float)(32 - kb) * (1.0f / 32.0f);

    // running sin/cos of t*dv, t starting at t0
    float st, ct;
    sincosf((float)t0 * dv, &st, &ct);

    __syncthreads();

    #pragma unroll 1
    for (int g = 0; g < 8; ++g) {
        float acc0 = 0.0f, acc1 = 0.0f, acc2 = 0.0f, acc3 = 0.0f;
        const int r0 = g * 4;
        #pragma unroll
        for (int q = 0; q < 8; ++q) {
            float4 rA = *(const float4*)&xs[(r0 + 0) * NCH + q * 4];
            float4 rB = *(const float4*)&xs[(r0 + 1) * NCH + q * 4];
            float4 rC = *(const float4*)&xs[(r0 + 2) * NCH + q * 4];
            float4 rD = *(const float4*)&xs[(r0 + 3) * NCH + q * 4];
            float4 rE = *(const float4*)&xs[(r0 + 4) * NCH + q * 4];
            float4 rF = *(const float4*)&xs[(r0 + 5) * NCH + q * 4];
            const float* wq = &w[q * 12];
            acc0 = fmaf(rA.x, wq[0], acc0); acc0 = fmaf(rB.x, wq[1], acc0); acc0 = fmaf(rC.x, wq[2], acc0);
            acc1 = fmaf(rB.x, wq[0], acc1); acc1 = fmaf(rC.x, wq[1], acc1); acc1 = fmaf(rD.x, wq[2], acc1);
            acc2 = fmaf(rC.x, wq[0], acc2); acc2 = fmaf(rD.x, wq[1], acc2); acc2 = fmaf(rE.x, wq[2], acc2);
            acc3 = fmaf(rD.x, wq[0], acc3); acc3 = fmaf(rE.x, wq[1], acc3); acc3 = fmaf(rF.x, wq[2], acc3);

            acc0 = fmaf(rA.y, wq[3], acc0); acc0 = fmaf(rB.y, wq[4], acc0); acc0 = fmaf(rC.y, wq[5], acc0);
            acc1 = fmaf(rB.y, wq[3], acc1); acc1 = fmaf(rC.y, wq[4], acc1); acc1 = fmaf(rD.y, wq[5], acc1);
            acc2 = fmaf(rC.y, wq[3], acc2); acc2 = fmaf(rD.y, wq[4], acc2); acc2 = fmaf(rE.y, wq[5], acc2);
            acc3 = fmaf(rD.y, wq[3], acc3); acc3 = fmaf(rE.y, wq[4], acc3); acc3 = fmaf(rF.y, wq[5], acc3);

            acc0 = fmaf(rA.z, wq[6], acc0); acc0 = fmaf(rB.z, wq[7], acc0); acc0 = fmaf(rC.z, wq[8], acc0);
            acc1 = fmaf(rB.z, wq[6], acc1); acc1 = fmaf(rC.z, wq[7], acc1); acc1 = fmaf(rD.z, wq[8], acc1);
            acc2 = fmaf(rC.z, wq[6], acc2); acc2 = fmaf(rD.z, wq[7], acc2); acc2 = fmaf(rE.z, wq[8], acc2);
            acc3 = fmaf(rD.z, wq[6], acc3); acc3 = fmaf(rE.z, wq[7], acc3); acc3 = fmaf(rF.z, wq[8], acc3);

            acc0 = fmaf(rA.w, wq[9], acc0); acc0 = fmaf(rB.w, wq[10], acc0); acc0 = fmaf(rC.w, wq[11], acc0);
            acc1 = fmaf(rB.w, wq[9], acc1); acc1 = fmaf(rC.w, wq[10], acc1); acc1 = fmaf(rD.w, wq[11], acc1);
            acc2 = fmaf(rC.w, wq[9], acc2); acc2 = fmaf(rD.w, wq[10], acc2); acc2 = fmaf(rE.w, wq[11], acc2);
            acc3 = fmaf(rD.w, wq[9], acc3); acc3 = fmaf(rE.w, wq[10], acc3); acc3 = fmaf(rF.w, wq[11], acc3);
        }
        float accs[4] = {acc0, acc1, acc2, acc3};
        #pragma unroll
        for (int m = 0; m < 4; ++m) {
            int tt = g * 4 + m;
            float temp = ttbl[sm[tt * 4 + 0] * DM + d] + ttbl[sm[tt * 4 + 1] * DM + d] +
                         ttbl[sm[tt * 4 + 2] * DM + d] + ttbl[sm[tt * 4 + 3] * DM + d];
            float ft  = odd ? ct : st;
            float cyc = fmaf(wt, ft, wk * f0);
            out[((size_t)(b * T) + t0 + tt) * DM + d] = accs[m] + temp + cyc;
            // rotate (st,ct) by dv
            float ns = fmaf(ct, sd_, st * cd_);
            float nc = fmaf(ct, cd_, -(st * sd_));
            st = ns; ct = nc;
        }
    }
}

extern "C" void kernel_launch(void* const* d_in, const int* in_sizes, int n_in,
                              void* d_out, int out_size, void* d_ws, size_t ws_size,
                              hipStream_t stream) {
    const float* x      = (const float*)d_in[0];
    const int*   xmark  = (const int*)d_in[1];
    const float* conv_w = (const float*)d_in[2];
    float*       out    = (float*)d_out;
    int*         cnt    = (int*)d_ws;

    hipMemsetAsync(cnt, 0, 64, stream);
    dft_nyq_kernel<<<dim3(BATCH * NCH), dim3(256), 0, stream>>>(x, cnt);
    fused_kernel<<<dim3(T / 32, BATCH), dim3(512), 0, stream>>>(x, xmark, conv_w, cnt, out);
}

// Round 3
// 92.953 us; speedup vs baseline: 1.2591x; 1.0094x over previous
//
#include <hip/hip_runtime.h>
#include <math.h>

#define T 512
#define NCH 32
#define BATCH 16
#define DM 512

// ---------------------------------------------------------------------------
// Kernel A: two-stage DFT (8 x 64 decimation) per (b,n).
// Only question: does Nyquist bin (k=256) strictly beat bins 0..255?
// (all non-Nyquist bins clamp to period 512 -> pidx=t; Nyquist -> pidx=0)
// ---------------------------------------------------------------------------
__global__ __launch_bounds__(256) void dft2_kernel(const float* __restrict__ x,
                                                   int* __restrict__ cnt) {
    __shared__ float  xv[T];        // xv[v*64+u] = x[8u+v]
    __shared__ float2 zs[T];        // zs[v*64+j] = Z_v[j]
    __shared__ float  s_mag[256];

    const int tid = threadIdx.x;
    const int b   = blockIdx.x >> 5;
    const int n   = blockIdx.x & 31;

    // stage + transpose
    for (int t = tid; t < T; t += 256) {
        float val = x[(b * T + t) * NCH + n];
        xv[(t & 7) * 64 + (t >> 3)] = val;
    }
    __syncthreads();

    // ---- stage 1: Z_v[j] = sum_u xv[v][u] * e^{-2*pi*i*j*u/64} ----
    const int j = tid & 63;
    float sd, cd;
    sincospif(-(float)j * (1.0f / 32.0f), &sd, &cd);   // e^{-2pi i j/64}

    #pragma unroll
    for (int h = 0; h < 2; ++h) {
        const int v = (tid >> 6) + h * 4;
        const float4* xp = (const float4*)&xv[v * 64];
        float wr = 1.0f, wi = 0.0f, zr = 0.0f, zi = 0.0f;
        #pragma unroll 4
        for (int g = 0; g < 16; ++g) {
            float4 c = xp[g];    // wave-uniform broadcast b128
            zr = fmaf(c.x, wr, zr); zi = fmaf(c.x, wi, zi);
            { float nr = fmaf(wr, cd, -(wi * sd)); float ni = fmaf(wr, sd, wi * cd); wr = nr; wi = ni; }
            zr = fmaf(c.y, wr, zr); zi = fmaf(c.y, wi, zi);
            { float nr = fmaf(wr, cd, -(wi * sd)); float ni = fmaf(wr, sd, wi * cd); wr = nr; wi = ni; }
            zr = fmaf(c.z, wr, zr); zi = fmaf(c.z, wi, zi);
            { float nr = fmaf(wr, cd, -(wi * sd)); float ni = fmaf(wr, sd, wi * cd); wr = nr; wi = ni; }
            zr = fmaf(c.w, wr, zr); zi = fmaf(c.w, wi, zi);
            { float nr = fmaf(wr, cd, -(wi * sd)); float ni = fmaf(wr, sd, wi * cd); wr = nr; wi = ni; }
        }
        zs[v * 64 + j] = make_float2(zr, zi);
    }
    __syncthreads();

    // ---- stage 2: X[k] = sum_v e^{-2*pi*i*k*v/512} * Z_v[k&63], k = tid ----
    float s2, c2;
    sincospif(-(float)tid * (1.0f / 256.0f), &s2, &c2); // e^{-2pi i k/512}
    float tr = 1.0f, ti = 0.0f, ar = 0.0f, ai = 0.0f;
    #pragma unroll
    for (int v = 0; v < 8; ++v) {
        float2 z = zs[v * 64 + j];
        ar = fmaf(tr, z.x, ar); ar = fmaf(-ti, z.y, ar);
        ai = fmaf(tr, z.y, ai); ai = fmaf(ti, z.x, ai);
        float nr = fmaf(tr, c2, -(ti * s2));
        float ni = fmaf(tr, s2, ti * c2);
        tr = nr; ti = ni;
    }
    s_mag[tid] = ar * ar + ai * ai;
    __syncthreads();

    for (int s2r = 128; s2r > 0; s2r >>= 1) {
        if (tid < s2r) s_mag[tid] = fmaxf(s_mag[tid], s_mag[tid + s2r]);
        __syncthreads();
    }
    if (tid == 0) {
        // Nyquist: X[256] = sum_v (-1)^v * Z_v[0]  (purely real)
        float ny = zs[0].x - zs[64].x + zs[128].x - zs[192].x +
                   zs[256].x - zs[320].x + zs[384].x - zs[448].x;
        if (ny * ny > s_mag[0]) atomicAdd(&cnt[b], 1);
    }
}

// ---------------------------------------------------------------------------
// Kernel B: fused conv1d(circular,k=3) + temporal + cycle embedding.
// 256 threads/block; each thread handles d-columns (tid, tid+256).
// Row-pipelined sliding window: each xs row chunk is read from LDS ONCE.
// ---------------------------------------------------------------------------
__global__ __launch_bounds__(256) void fused2_kernel(const float* __restrict__ x,
                                                     const int*   __restrict__ xmark,
                                                     const float* __restrict__ conv_w,
                                                     const int*   __restrict__ cnt,
                                                     float*       __restrict__ out) {
    __shared__ float xs[34 * NCH];     // rows t0-1 .. t0+32 (wrapped)
    __shared__ int   sm[32 * 4];
    __shared__ float ttbl[7 * DM];     // temporal table rows p=0..6

    const int tid = threadIdx.x;
    const int t0  = blockIdx.x * 32;
    const int b   = blockIdx.y;
    const int d0  = tid;
    const int d1  = tid + 256;

    // conv weights for both columns -> registers (issue loads early)
    float wA[96], wB[96];
    {
        const float4* wp0 = (const float4*)(conv_w + d0 * 96);
        const float4* wp1 = (const float4*)(conv_w + d1 * 96);
        #pragma unroll
        for (int i = 0; i < 24; ++i) {
            float4 v0 = wp0[i], v1 = wp1[i];
            wA[4*i+0] = v0.x; wA[4*i+1] = v0.y; wA[4*i+2] = v0.z; wA[4*i+3] = v0.w;
            wB[4*i+0] = v1.x; wB[4*i+1] = v1.y; wB[4*i+2] = v1.z; wB[4*i+3] = v1.w;
        }
    }

    // stage x slab
    for (int i = tid; i < 34 * NCH; i += 256) {
        int row = i >> 5, n = i & 31;
        int t = (t0 + row - 1 + T) & (T - 1);
        xs[i] = x[(b * T + t) * NCH + n];
    }
    if (tid < 128) sm[tid] = xmark[(b * T + t0) * 4 + tid];

    // fixed-embedding generators: f(p,d) = sin(p*dv + (d&1)*pi/2)
    const bool  odd = (tid & 1);                    // d1 = d0+256: same parity
    const float dvA = expf((float)(d0 & ~1) * (-9.210340371976184f / 512.0f));
    const float dvB = expf((float)(d1 & ~1) * (-9.210340371976184f / 512.0f));
    float sdA, cdA, sdB, cdB;
    sincosf(dvA, &sdA, &cdA);
    sincosf(dvB, &sdB, &cdB);

    // temporal table rows 0..6 for both columns (rotation from phi=0)
    {
        float s = 0.0f, c = 1.0f;
        #pragma unroll
        for (int p = 0; p < 7; ++p) {
            ttbl[p * DM + d0] = odd ? c : s;
            float ns = fmaf(c, sdA, s * cdA);
            float nc = fmaf(c, cdA, -(s * sdA));
            s = ns; c = nc;
        }
        s = 0.0f; c = 1.0f;
        #pragma unroll
        for (int p = 0; p < 7; ++p) {
            ttbl[p * DM + d1] = odd ? c : s;
            float ns = fmaf(c, sdB, s * cdB);
            float nc = fmaf(c, cdB, -(s * sdB));
            s = ns; c = nc;
        }
    }

    const float f0   = odd ? 1.0f : 0.0f;
    const int   kb   = cnt[b];
    const float wt   = (float)(32 - kb) * (1.0f / 32.0f);
    const float wkf0 = (float)kb * (1.0f / 32.0f) * f0;

    // running sin/cos of t*dv starting at t0 (first emitted output)
    float stA, ctA, stB, ctB;
    sincosf((float)t0 * dvA, &stA, &ctA);
    sincosf((float)t0 * dvB, &stB, &ctB);

    __syncthreads();

    // pipeline partials: A0=output r (j=0), A1=output r-1 (j=1), A2=output r-2 (j=2)
    float A0a = 0.0f, A1a = 0.0f, A2a = 0.0f;
    float A0b = 0.0f, A1b = 0.0f, A2b = 0.0f;

    #pragma unroll 2
    for (int r = 0; r < 34; ++r) {
        const float4* rowp = (const float4*)&xs[r * NCH];
        A0a = 0.0f; A0b = 0.0f;
        #pragma unroll
        for (int q = 0; q < 8; ++q) {
            float4 c = rowp[q];     // wave-uniform broadcast b128
            const int w0 = 12 * q;
            A0a = fmaf(c.x, wA[w0+0], A0a); A1a = fmaf(c.x, wA[w0+1],  A1a); A2a = fmaf(c.x, wA[w0+2],  A2a);
            A0a = fmaf(c.y, wA[w0+3], A0a); A1a = fmaf(c.y, wA[w0+4],  A1a); A2a = fmaf(c.y, wA[w0+5],  A2a);
            A0a = fmaf(c.z, wA[w0+6], A0a); A1a = fmaf(c.z, wA[w0+7],  A1a); A2a = fmaf(c.z, wA[w0+8],  A2a);
            A0a = fmaf(c.w, wA[w0+9], A0a); A1a = fmaf(c.w, wA[w0+10], A1a); A2a = fmaf(c.w, wA[w0+11], A2a);
            A0b = fmaf(c.x, wB[w0+0], A0b); A1b = fmaf(c.x, wB[w0+1],  A1b); A2b = fmaf(c.x, wB[w0+2],  A2b);
            A0b = fmaf(c.y, wB[w0+3], A0b); A1b = fmaf(c.y, wB[w0+4],  A1b); A2b = fmaf(c.y, wB[w0+5],  A2b);
            A0b = fmaf(c.z, wB[w0+6], A0b); A1b = fmaf(c.z, wB[w0+7],  A1b); A2b = fmaf(c.z, wB[w0+8],  A2b);
            A0b = fmaf(c.w, wB[w0+9], A0b); A1b = fmaf(c.w, wB[w0+10], A1b); A2b = fmaf(c.w, wB[w0+11], A2b);
        }
        if (r >= 2) {
            const int tt = r - 2;
            int4 smv = *(const int4*)&sm[tt * 4];
            float tempA = ttbl[smv.x * DM + d0] + ttbl[smv.y * DM + d0] +
                          ttbl[smv.z * DM + d0] + ttbl[smv.w * DM + d0];
            float tempB = ttbl[smv.x * DM + d1] + ttbl[smv.y * DM + d1] +
                          ttbl[smv.z * DM + d1] + ttbl[smv.w * DM + d1];
            float ftA = odd ? ctA : stA;
            float ftB = odd ? ctB : stB;
            size_t base = ((size_t)(b * T) + t0 + tt) * DM;
            out[base + d0] = A2a + tempA + fmaf(wt, ftA, wkf0);
            out[base + d1] = A2b + tempB + fmaf(wt, ftB, wkf0);
            // rotate running sin/cos by dv
            { float ns = fmaf(ctA, sdA, stA * cdA); float nc = fmaf(ctA, cdA, -(stA * sdA)); stA = ns; ctA = nc; }
            { float ns = fmaf(ctB, sdB, stB * cdB); float nc = fmaf(ctB, cdB, -(stB * sdB)); stB = ns; ctB = nc; }
        }
        // shift pipeline
        A2a = A1a; A1a = A0a;
        A2b = A1b; A1b = A0b;
    }
}

extern "C" void kernel_launch(void* const* d_in, const int* in_sizes, int n_in,
                              void* d_out, int out_size, void* d_ws, size_t ws_size,
                              hipStream_t stream) {
    const float* x      = (const float*)d_in[0];
    const int*   xmark  = (const int*)d_in[1];
    const float* conv_w = (const float*)d_in[2];
    float*       out    = (float*)d_out;
    int*         cnt    = (int*)d_ws;

    hipMemsetAsync(cnt, 0, 64, stream);
    dft2_kernel<<<dim3(BATCH * NCH), dim3(256), 0, stream>>>(x, cnt);
    fused2_kernel<<<dim3(T / 32, BATCH), dim3(256), 0, stream>>>(x, xmark, conv_w, cnt, out);
}

// Round 4
// 91.406 us; speedup vs baseline: 1.2804x; 1.0169x over previous
//
#include <hip/hip_runtime.h>
#include <math.h>

#define T 512
#define NCH 32
#define BATCH 16
#define DM 512

// ---------------------------------------------------------------------------
// Kernel A: two-stage DFT (8 x 64 decimation) per (b,n), with real-input
// conjugate symmetry: Z_v[64-j] = conj(Z_v[j]) -> only j=0..32 computed.
// Writes flags[b*32+n] = 1 iff Nyquist bin strictly beats bins 0..255
// (non-Nyquist bins clamp to period 512 -> pidx=t; Nyquist -> pidx=0).
// Unconditional write => no memset of d_ws needed (poison-safe).
// ---------------------------------------------------------------------------
__global__ __launch_bounds__(256) void dft2_kernel(const float* __restrict__ x,
                                                   int* __restrict__ flags) {
    __shared__ float  xv[T];        // xv[v*64+u] = x[8u+v]
    __shared__ float2 zs[T];        // zs[v*64+j] = Z_v[j]
    __shared__ float  s_mag[256];

    const int tid = threadIdx.x;
    const int b   = blockIdx.x >> 5;
    const int n   = blockIdx.x & 31;

    // stage + transpose
    for (int t = tid; t < T; t += 256) {
        float val = x[(b * T + t) * NCH + n];
        xv[(t & 7) * 64 + (t >> 3)] = val;
    }
    __syncthreads();

    // ---- stage 1: thread (v = tid>>5, j = tid&31) computes Z_v[j] ----
    // (j=0 rotation degenerates to the plain sum; alt-sum gives Z_v[32])
    const int v = tid >> 5;
    const int j = tid & 31;
    float sd, cd;
    sincospif(-(float)j * (1.0f / 32.0f), &sd, &cd);   // e^{-2pi i j/64}

    {
        const float4* xp = (const float4*)&xv[v * 64];
        float wr = 1.0f, wi = 0.0f, zr = 0.0f, zi = 0.0f, alt = 0.0f;
        #pragma unroll 4
        for (int g = 0; g < 16; ++g) {
            float4 c = xp[g];    // wave-uniform broadcast b128
            alt += (c.x + c.z) - (c.y + c.w);
            zr = fmaf(c.x, wr, zr); zi = fmaf(c.x, wi, zi);
            { float nr = fmaf(wr, cd, -(wi * sd)); float ni = fmaf(wr, sd, wi * cd); wr = nr; wi = ni; }
            zr = fmaf(c.y, wr, zr); zi = fmaf(c.y, wi, zi);
            { float nr = fmaf(wr, cd, -(wi * sd)); float ni = fmaf(wr, sd, wi * cd); wr = nr; wi = ni; }
            zr = fmaf(c.z, wr, zr); zi = fmaf(c.z, wi, zi);
            { float nr = fmaf(wr, cd, -(wi * sd)); float ni = fmaf(wr, sd, wi * cd); wr = nr; wi = ni; }
            zr = fmaf(c.w, wr, zr); zi = fmaf(c.w, wi, zi);
            { float nr = fmaf(wr, cd, -(wi * sd)); float ni = fmaf(wr, sd, wi * cd); wr = nr; wi = ni; }
        }
        zs[v * 64 + j] = make_float2(zr, zi);
        zs[v * 64 + ((64 - j) & 63)] = make_float2(zr, -zi);   // conj mirror
        if (j == 0) zs[v * 64 + 32] = make_float2(alt, 0.0f);  // Z_v[32]
    }
    __syncthreads();

    // ---- stage 2: X[k] = sum_v e^{-2*pi*i*k*v/512} * Z_v[k&63], k = tid ----
    const int j2 = tid & 63;
    float s2, c2;
    sincospif(-(float)tid * (1.0f / 256.0f), &s2, &c2); // e^{-2pi i k/512}
    float tr = 1.0f, ti = 0.0f, ar = 0.0f, ai = 0.0f;
    #pragma unroll
    for (int vv = 0; vv < 8; ++vv) {
        float2 z = zs[vv * 64 + j2];
        ar = fmaf(tr, z.x, ar); ar = fmaf(-ti, z.y, ar);
        ai = fmaf(tr, z.y, ai); ai = fmaf(ti, z.x, ai);
        float nr = fmaf(tr, c2, -(ti * s2));
        float ni = fmaf(tr, s2, ti * c2);
        tr = nr; ti = ni;
    }
    s_mag[tid] = ar * ar + ai * ai;
    __syncthreads();

    for (int s2r = 128; s2r > 0; s2r >>= 1) {
        if (tid < s2r) s_mag[tid] = fmaxf(s_mag[tid], s_mag[tid + s2r]);
        __syncthreads();
    }
    if (tid == 0) {
        // Nyquist: X[256] = sum_v (-1)^v * Z_v[0]  (purely real)
        float ny = zs[0].x - zs[64].x + zs[128].x - zs[192].x +
                   zs[256].x - zs[320].x + zs[384].x - zs[448].x;
        flags[blockIdx.x] = (ny * ny > s_mag[0]) ? 1 : 0;  // unconditional
    }
}

// ---------------------------------------------------------------------------
// Kernel B: fused conv1d(circular,k=3) + temporal + cycle embedding.
// 256 threads/block; each thread handles d-columns (tid, tid+256).
// Row-pipelined sliding window: each xs row chunk is read from LDS ONCE.
// Reduces its batch's 32 Nyquist flags in-kernel (no memset / atomics).
// ---------------------------------------------------------------------------
__global__ __launch_bounds__(256) void fused2_kernel(const float* __restrict__ x,
                                                     const int*   __restrict__ xmark,
                                                     const float* __restrict__ conv_w,
                                                     const int*   __restrict__ flags,
                                                     float*       __restrict__ out) {
    __shared__ float xs[34 * NCH];     // rows t0-1 .. t0+32 (wrapped)
    __shared__ int   sm[32 * 4];
    __shared__ float ttbl[7 * DM];     // temporal table rows p=0..6
    __shared__ int   s_kb;

    const int tid = threadIdx.x;
    const int t0  = blockIdx.x * 32;
    const int b   = blockIdx.y;
    const int d0  = tid;
    const int d1  = tid + 256;

    // reduce this batch's 32 Nyquist flags (wave 0 only)
    if (tid < 64) {
        int f = (tid < 32) ? flags[b * 32 + tid] : 0;
        f += __shfl_down(f, 32);
        f += __shfl_down(f, 16);
        f += __shfl_down(f, 8);
        f += __shfl_down(f, 4);
        f += __shfl_down(f, 2);
        f += __shfl_down(f, 1);
        if (tid == 0) s_kb = f;
    }

    // conv weights for both columns -> registers (issue loads early)
    float wA[96], wB[96];
    {
        const float4* wp0 = (const float4*)(conv_w + d0 * 96);
        const float4* wp1 = (const float4*)(conv_w + d1 * 96);
        #pragma unroll
        for (int i = 0; i < 24; ++i) {
            float4 v0 = wp0[i], v1 = wp1[i];
            wA[4*i+0] = v0.x; wA[4*i+1] = v0.y; wA[4*i+2] = v0.z; wA[4*i+3] = v0.w;
            wB[4*i+0] = v1.x; wB[4*i+1] = v1.y; wB[4*i+2] = v1.z; wB[4*i+3] = v1.w;
        }
    }

    // stage x slab
    for (int i = tid; i < 34 * NCH; i += 256) {
        int row = i >> 5, n = i & 31;
        int t = (t0 + row - 1 + T) & (T - 1);
        xs[i] = x[(b * T + t) * NCH + n];
    }
    if (tid < 128) sm[tid] = xmark[(b * T + t0) * 4 + tid];

    // fixed-embedding generators: f(p,d) = sin(p*dv + (d&1)*pi/2)
    const bool  odd = (tid & 1);                    // d1 = d0+256: same parity
    const float dvA = expf((float)(d0 & ~1) * (-9.210340371976184f / 512.0f));
    const float dvB = expf((float)(d1 & ~1) * (-9.210340371976184f / 512.0f));
    float sdA, cdA, sdB, cdB;
    sincosf(dvA, &sdA, &cdA);
    sincosf(dvB, &sdB, &cdB);

    // temporal table rows 0..6 for both columns (rotation from phi=0)
    {
        float s = 0.0f, c = 1.0f;
        #pragma unroll
        for (int p = 0; p < 7; ++p) {
            ttbl[p * DM + d0] = odd ? c : s;
            float ns = fmaf(c, sdA, s * cdA);
            float nc = fmaf(c, cdA, -(s * sdA));
            s = ns; c = nc;
        }
        s = 0.0f; c = 1.0f;
        #pragma unroll
        for (int p = 0; p < 7; ++p) {
            ttbl[p * DM + d1] = odd ? c : s;
            float ns = fmaf(c, sdB, s * cdB);
            float nc = fmaf(c, cdB, -(s * sdB));
            s = ns; c = nc;
        }
    }

    // running sin/cos of t*dv starting at t0 (first emitted output)
    float stA, ctA, stB, ctB;
    sincosf((float)t0 * dvA, &stA, &ctA);
    sincosf((float)t0 * dvB, &stB, &ctB);

    __syncthreads();

    const float f0   = odd ? 1.0f : 0.0f;
    const int   kb   = s_kb;
    const float wt   = (float)(32 - kb) * (1.0f / 32.0f);
    const float wkf0 = (float)kb * (1.0f / 32.0f) * f0;

    // pipeline partials: A0=output r (j=0), A1=output r-1 (j=1), A2=output r-2 (j=2)
    float A0a = 0.0f, A1a = 0.0f, A2a = 0.0f;
    float A0b = 0.0f, A1b = 0.0f, A2b = 0.0f;

    #pragma unroll 2
    for (int r = 0; r < 34; ++r) {
        const float4* rowp = (const float4*)&xs[r * NCH];
        A0a = 0.0f; A0b = 0.0f;
        #pragma unroll
        for (int q = 0; q < 8; ++q) {
            float4 c = rowp[q];     // wave-uniform broadcast b128
            const int w0 = 12 * q;
            A0a = fmaf(c.x, wA[w0+0], A0a); A1a = fmaf(c.x, wA[w0+1],  A1a); A2a = fmaf(c.x, wA[w0+2],  A2a);
            A0a = fmaf(c.y, wA[w0+3], A0a); A1a = fmaf(c.y, wA[w0+4],  A1a); A2a = fmaf(c.y, wA[w0+5],  A2a);
            A0a = fmaf(c.z, wA[w0+6], A0a); A1a = fmaf(c.z, wA[w0+7],  A1a); A2a = fmaf(c.z, wA[w0+8],  A2a);
            A0a = fmaf(c.w, wA[w0+9], A0a); A1a = fmaf(c.w, wA[w0+10], A1a); A2a = fmaf(c.w, wA[w0+11], A2a);
            A0b = fmaf(c.x, wB[w0+0], A0b); A1b = fmaf(c.x, wB[w0+1],  A1b); A2b = fmaf(c.x, wB[w0+2],  A2b);
            A0b = fmaf(c.y, wB[w0+3], A0b); A1b = fmaf(c.y, wB[w0+4],  A1b); A2b = fmaf(c.y, wB[w0+5],  A2b);
            A0b = fmaf(c.z, wB[w0+6], A0b); A1b = fmaf(c.z, wB[w0+7],  A1b); A2b = fmaf(c.z, wB[w0+8],  A2b);
            A0b = fmaf(c.w, wB[w0+9], A0b); A1b = fmaf(c.w, wB[w0+10], A1b); A2b = fmaf(c.w, wB[w0+11], A2b);
        }
        if (r >= 2) {
            const int tt = r - 2;
            int4 smv = *(const int4*)&sm[tt * 4];
            float tempA = ttbl[smv.x * DM + d0] + ttbl[smv.y * DM + d0] +
                          ttbl[smv.z * DM + d0] + ttbl[smv.w * DM + d0];
            float tempB = ttbl[smv.x * DM + d1] + ttbl[smv.y * DM + d1] +
                          ttbl[smv.z * DM + d1] + ttbl[smv.w * DM + d1];
            float ftA = odd ? ctA : stA;
            float ftB = odd ? ctB : stB;
            size_t base = ((size_t)(b * T) + t0 + tt) * DM;
            out[base + d0] = A2a + tempA + fmaf(wt, ftA, wkf0);
            out[base + d1] = A2b + tempB + fmaf(wt, ftB, wkf0);
            // rotate running sin/cos by dv
            { float ns = fmaf(ctA, sdA, stA * cdA); float nc = fmaf(ctA, cdA, -(stA * sdA)); stA = ns; ctA = nc; }
            { float ns = fmaf(ctB, sdB, stB * cdB); float nc = fmaf(ctB, cdB, -(stB * sdB)); stB = ns; ctB = nc; }
        }
        // shift pipeline
        A2a = A1a; A1a = A0a;
        A2b = A1b; A1b = A0b;
    }
}

extern "C" void kernel_launch(void* const* d_in, const int* in_sizes, int n_in,
                              void* d_out, int out_size, void* d_ws, size_t ws_size,
                              hipStream_t stream) {
    const float* x      = (const float*)d_in[0];
    const int*   xmark  = (const int*)d_in[1];
    const float* conv_w = (const float*)d_in[2];
    float*       out    = (float*)d_out;
    int*         flags  = (int*)d_ws;

    dft2_kernel<<<dim3(BATCH * NCH), dim3(256), 0, stream>>>(x, flags);
    fused2_kernel<<<dim3(T / 32, BATCH), dim3(256), 0, stream>>>(x, xmark, conv_w, flags, out);
}

// Round 5
// 87.765 us; speedup vs baseline: 1.3335x; 1.0415x over previous
//
#include <hip/hip_runtime.h>
#include <math.h>

#define T 512
#define NCH 32
#define BATCH 16
#define DM 512

// ---------------------------------------------------------------------------
// Kernel A: two-stage DFT (8 x 64 decimation) per (b,n), with real-input
// conjugate symmetry: Z_v[64-j] = conj(Z_v[j]) -> only j=0..32 computed.
// Writes flags[b*32+n] = 1 iff Nyquist bin strictly beats bins 0..255
// (non-Nyquist bins clamp to period 512 -> pidx=t; Nyquist -> pidx=0).
// Unconditional write => no memset of d_ws needed (poison-safe).
// ---------------------------------------------------------------------------
__global__ __launch_bounds__(256) void dft2_kernel(const float* __restrict__ x,
                                                   int* __restrict__ flags) {
    __shared__ float  xv[T];        // xv[v*64+u] = x[8u+v]
    __shared__ float2 zs[T];        // zs[v*64+j] = Z_v[j]
    __shared__ float  s_mag[256];

    const int tid = threadIdx.x;
    const int b   = blockIdx.x >> 5;
    const int n   = blockIdx.x & 31;

    // stage + transpose
    for (int t = tid; t < T; t += 256) {
        float val = x[(b * T + t) * NCH + n];
        xv[(t & 7) * 64 + (t >> 3)] = val;
    }
    __syncthreads();

    // ---- stage 1: thread (v = tid>>5, j = tid&31) computes Z_v[j] ----
    const int v = tid >> 5;
    const int j = tid & 31;
    float sd, cd;
    sincospif(-(float)j * (1.0f / 32.0f), &sd, &cd);   // e^{-2pi i j/64}

    {
        const float4* xp = (const float4*)&xv[v * 64];
        float wr = 1.0f, wi = 0.0f, zr = 0.0f, zi = 0.0f, alt = 0.0f;
        #pragma unroll 4
        for (int g = 0; g < 16; ++g) {
            float4 c = xp[g];    // wave-uniform broadcast b128
            alt += (c.x + c.z) - (c.y + c.w);
            zr = fmaf(c.x, wr, zr); zi = fmaf(c.x, wi, zi);
            { float nr = fmaf(wr, cd, -(wi * sd)); float ni = fmaf(wr, sd, wi * cd); wr = nr; wi = ni; }
            zr = fmaf(c.y, wr, zr); zi = fmaf(c.y, wi, zi);
            { float nr = fmaf(wr, cd, -(wi * sd)); float ni = fmaf(wr, sd, wi * cd); wr = nr; wi = ni; }
            zr = fmaf(c.z, wr, zr); zi = fmaf(c.z, wi, zi);
            { float nr = fmaf(wr, cd, -(wi * sd)); float ni = fmaf(wr, sd, wi * cd); wr = nr; wi = ni; }
            zr = fmaf(c.w, wr, zr); zi = fmaf(c.w, wi, zi);
            { float nr = fmaf(wr, cd, -(wi * sd)); float ni = fmaf(wr, sd, wi * cd); wr = nr; wi = ni; }
        }
        zs[v * 64 + j] = make_float2(zr, zi);
        zs[v * 64 + ((64 - j) & 63)] = make_float2(zr, -zi);   // conj mirror
        if (j == 0) zs[v * 64 + 32] = make_float2(alt, 0.0f);  // Z_v[32]
    }
    __syncthreads();

    // ---- stage 2: X[k] = sum_v e^{-2*pi*i*k*v/512} * Z_v[k&63], k = tid ----
    const int j2 = tid & 63;
    float s2, c2;
    sincospif(-(float)tid * (1.0f / 256.0f), &s2, &c2); // e^{-2pi i k/512}
    float tr = 1.0f, ti = 0.0f, ar = 0.0f, ai = 0.0f;
    #pragma unroll
    for (int vv = 0; vv < 8; ++vv) {
        float2 z = zs[vv * 64 + j2];
        ar = fmaf(tr, z.x, ar); ar = fmaf(-ti, z.y, ar);
        ai = fmaf(tr, z.y, ai); ai = fmaf(ti, z.x, ai);
        float nr = fmaf(tr, c2, -(ti * s2));
        float ni = fmaf(tr, s2, ti * c2);
        tr = nr; ti = ni;
    }
    s_mag[tid] = ar * ar + ai * ai;
    __syncthreads();

    for (int s2r = 128; s2r > 0; s2r >>= 1) {
        if (tid < s2r) s_mag[tid] = fmaxf(s_mag[tid], s_mag[tid + s2r]);
        __syncthreads();
    }
    if (tid == 0) {
        // Nyquist: X[256] = sum_v (-1)^v * Z_v[0]  (purely real)
        float ny = zs[0].x - zs[64].x + zs[128].x - zs[192].x +
                   zs[256].x - zs[320].x + zs[384].x - zs[448].x;
        flags[blockIdx.x] = (ny * ny > s_mag[0]) ? 1 : 0;  // unconditional
    }
}

// ---------------------------------------------------------------------------
// Kernel B: fused conv1d(circular,k=3) + temporal + cycle embedding.
// grid (16 t-chunks, 16 b, 2 d-halves) x 256 threads, ONE d-column/thread.
// 512 blocks -> 2 blocks/CU -> 2 waves/SIMD (latency hiding; fused2 had 1).
// Row-pipelined sliding window: each xs row chunk is read from LDS ONCE.
// ---------------------------------------------------------------------------
__global__ __launch_bounds__(256) void fused3_kernel(const float* __restrict__ x,
                                                     const int*   __restrict__ xmark,
                                                     const float* __restrict__ conv_w,
                                                     const int*   __restrict__ flags,
                                                     float*       __restrict__ out) {
    __shared__ float xs[34 * NCH];     // rows t0-1 .. t0+32 (wrapped)
    __shared__ int   sm[32 * 4];
    __shared__ float ttbl[7 * 256];    // temporal table rows p=0..6, this d-half
    __shared__ int   s_kb;

    const int tid = threadIdx.x;
    const int t0  = blockIdx.x * 32;
    const int b   = blockIdx.y;
    const int d   = blockIdx.z * 256 + tid;

    // reduce this batch's 32 Nyquist flags (wave 0 only)
    if (tid < 64) {
        int f = (tid < 32) ? flags[b * 32 + tid] : 0;
        f += __shfl_down(f, 32);
        f += __shfl_down(f, 16);
        f += __shfl_down(f, 8);
        f += __shfl_down(f, 4);
        f += __shfl_down(f, 2);
        f += __shfl_down(f, 1);
        if (tid == 0) s_kb = f;
    }

    // conv weights -> 96 registers (issue loads early)
    float w[96];
    {
        const float4* wp = (const float4*)(conv_w + d * 96);
        #pragma unroll
        for (int i = 0; i < 24; ++i) {
            float4 v0 = wp[i];
            w[4*i+0] = v0.x; w[4*i+1] = v0.y; w[4*i+2] = v0.z; w[4*i+3] = v0.w;
        }
    }

    // stage x slab
    for (int i = tid; i < 34 * NCH; i += 256) {
        int row = i >> 5, n = i & 31;
        int t = (t0 + row - 1 + T) & (T - 1);
        xs[i] = x[(b * T + t) * NCH + n];
    }
    if (tid < 128) sm[tid] = xmark[(b * T + t0) * 4 + tid];

    // fixed-embedding generator: f(p,d) = sin(p*dv + (d&1)*pi/2)
    const bool  odd = (d & 1);
    const float dv  = expf((float)(d & ~1) * (-9.210340371976184f / 512.0f));
    float sd_, cd_;
    sincosf(dv, &sd_, &cd_);

    // temporal table rows 0..6 for this column (rotation from phi=0)
    {
        float s = 0.0f, c = 1.0f;
        #pragma unroll
        for (int p = 0; p < 7; ++p) {
            ttbl[p * 256 + tid] = odd ? c : s;
            float ns = fmaf(c, sd_, s * cd_);
            float nc = fmaf(c, cd_, -(s * sd_));
            s = ns; c = nc;
        }
    }

    // running sin/cos of t*dv starting at t0 (first emitted output)
    float st, ct;
    sincosf((float)t0 * dv, &st, &ct);

    __syncthreads();

    const float f0   = odd ? 1.0f : 0.0f;
    const int   kb   = s_kb;
    const float wt   = (float)(32 - kb) * (1.0f / 32.0f);
    const float wkf0 = (float)kb * (1.0f / 32.0f) * f0;

    // pipeline partials: A0=output r (tap 0), A1=output r-1 (tap 1), A2=output r-2 (tap 2)
    float A0 = 0.0f, A1 = 0.0f, A2 = 0.0f;

    #pragma unroll 2
    for (int r = 0; r < 34; ++r) {
        const float4* rowp = (const float4*)&xs[r * NCH];
        A0 = 0.0f;
        #pragma unroll
        for (int q = 0; q < 8; ++q) {
            float4 c = rowp[q];     // wave-uniform broadcast b128
            const int w0 = 12 * q;
            A0 = fmaf(c.x, w[w0+0], A0); A1 = fmaf(c.x, w[w0+1],  A1); A2 = fmaf(c.x, w[w0+2],  A2);
            A0 = fmaf(c.y, w[w0+3], A0); A1 = fmaf(c.y, w[w0+4],  A1); A2 = fmaf(c.y, w[w0+5],  A2);
            A0 = fmaf(c.z, w[w0+6], A0); A1 = fmaf(c.z, w[w0+7],  A1); A2 = fmaf(c.z, w[w0+8],  A2);
            A0 = fmaf(c.w, w[w0+9], A0); A1 = fmaf(c.w, w[w0+10], A1); A2 = fmaf(c.w, w[w0+11], A2);
        }
        if (r >= 2) {
            const int tt = r - 2;
            int4 smv = *(const int4*)&sm[tt * 4];   // wave-uniform broadcast
            float temp = ttbl[smv.x * 256 + tid] + ttbl[smv.y * 256 + tid] +
                         ttbl[smv.z * 256 + tid] + ttbl[smv.w * 256 + tid];
            float ft = odd ? ct : st;
            out[((size_t)(b * T) + t0 + tt) * DM + d] = A2 + temp + fmaf(wt, ft, wkf0);
            // rotate running sin/cos by dv
            float ns = fmaf(ct, sd_, st * cd_);
            float nc = fmaf(ct, cd_, -(st * sd_));
            st = ns; ct = nc;
        }
        // shift pipeline
        A2 = A1; A1 = A0;
    }
}

extern "C" void kernel_launch(void* const* d_in, const int* in_sizes, int n_in,
                              void* d_out, int out_size, void* d_ws, size_t ws_size,
                              hipStream_t stream) {
    const float* x      = (const float*)d_in[0];
    const int*   xmark  = (const int*)d_in[1];
    const float* conv_w = (const float*)d_in[2];
    float*       out    = (float*)d_out;
    int*         flags  = (int*)d_ws;

    dft2_kernel<<<dim3(BATCH * NCH), dim3(256), 0, stream>>>(x, flags);
    fused3_kernel<<<dim3(T / 32, BATCH, 2), dim3(256), 0, stream>>>(x, xmark, conv_w, flags, out);
}